// Round 1
// baseline (1265.943 us; speedup 1.0000x reference)
//
#include <hip/hip_runtime.h>
#include <math.h>

namespace {

constexpr int N = 50000;
constexpr int E = 400000;
constexpr int G = 64;
constexpr int HID = 64;
constexpr int NHEAD = 4;
constexpr int HH = NHEAD * HID; // 256
constexpr float NEG = 0.2f;

__device__ __forceinline__ int fenc(float f) {
    int i = __float_as_int(f);
    return (i >= 0) ? i : (i ^ 0x7FFFFFFF);
}
__device__ __forceinline__ float fdec(int i) {
    return __int_as_float((i >= 0) ? i : (i ^ 0x7FFFFFFF));
}

// ---- edge attr projection: eap[e][4] ----
__global__ __launch_bounds__(256) void edge_feat_k(
    const float* __restrict__ ea,
    const float* __restrict__ W_et, const float* __restrict__ b_et,
    const float* __restrict__ W_uw, const float* __restrict__ b_uw,
    const float* __restrict__ W_ua, const float* __restrict__ b_ua,
    float* __restrict__ eap)
{
    int e = blockIdx.x * 256 + threadIdx.x;
    if (e >= E) return;
    float et = ea[e * 2 + 0], uw = ea[e * 2 + 1];
    float ua = 1.f / (1.f + expf(-(uw * W_ua[0] + b_ua[0])));
    eap[e * 4 + 0] = et * W_et[0] + b_et[0];
    eap[e * 4 + 1] = et * W_et[1] + b_et[1];
    eap[e * 4 + 2] = (uw * W_uw[0] + b_uw[0]) * ua;
    eap[e * 4 + 3] = (uw * W_uw[1] + b_uw[1]) * ua;
}

// ---- node projections: xl = x@Wl+bl, xr = x@Wr+br, (N x HH) ----
template <int IC>
__global__ __launch_bounds__(256) void node_proj_k(
    const float* __restrict__ x,
    const float* __restrict__ Wl, const float* __restrict__ bl,
    const float* __restrict__ Wr, const float* __restrict__ br,
    float* __restrict__ xl, float* __restrict__ xr)
{
    constexpr int NPB = 8;
    __shared__ float xs[NPB][IC];
    const int base = blockIdx.x * NPB;
    const int tid = threadIdx.x;
    for (int idx = tid; idx < NPB * IC; idx += 256) {
        int j = idx / IC, k = idx - j * IC;
        int n = base + j;
        xs[j][k] = (n < N) ? x[n * IC + k] : 0.f;
    }
    __syncthreads();
    float accl[NPB], accr[NPB];
#pragma unroll
    for (int j = 0; j < NPB; j++) { accl[j] = 0.f; accr[j] = 0.f; }
    for (int k = 0; k < IC; k++) {
        float wl = Wl[k * HH + tid];
        float wr = Wr[k * HH + tid];
#pragma unroll
        for (int j = 0; j < NPB; j++) {
            accl[j] += xs[j][k] * wl;
            accr[j] += xs[j][k] * wr;
        }
    }
    float bll = bl[tid], brr = br[tid];
#pragma unroll
    for (int j = 0; j < NPB; j++) {
        int n = base + j;
        if (n < N) {
            xl[n * HH + tid] = accl[j] + bll;
            xr[n * HH + tid] = accr[j] + brr;
        }
    }
}

// ---- per-layer init: smax = -inf(enc), denom = 0, acc = 0 ----
__global__ __launch_bounds__(256) void init_layer_k(
    int* __restrict__ smax, float* __restrict__ denom, float* __restrict__ acc)
{
    int i = blockIdx.x * 256 + threadIdx.x;
    if (i < N * NHEAD) { smax[i] = 0x80000000; denom[i] = 0.f; }
    if (i < N * HID) acc[i] = 0.f;
}

// ---- pass 1: scores + segment max (one 64-lane wave per edge) ----
__global__ __launch_bounds__(256) void edge_score_k(
    const float* __restrict__ xl, const float* __restrict__ xr,
    const float* __restrict__ eap, const float* __restrict__ We,
    const float* __restrict__ att,
    const int* __restrict__ src_idx, const int* __restrict__ dst_idx,
    float* __restrict__ score, int* __restrict__ smax)
{
    int e = blockIdx.x * 4 + (threadIdx.x >> 6);
    int c = threadIdx.x & 63;
    if (e >= E) return;
    int s = src_idx[e], d = dst_idx[e];
    float a0 = eap[e * 4 + 0], a1 = eap[e * 4 + 1];
    float a2 = eap[e * 4 + 2], a3 = eap[e * 4 + 3];
    float sc[NHEAD];
#pragma unroll
    for (int h = 0; h < NHEAD; h++) {
        int col = h * HID + c;
        float ee = a0 * We[col] + a1 * We[HH + col] + a2 * We[2 * HH + col] + a3 * We[3 * HH + col];
        float m = xl[s * HH + col] + xr[d * HH + col] + ee;
        m = (m > 0.f) ? m : NEG * m;
        sc[h] = m * att[col];
    }
#pragma unroll
    for (int off = 32; off > 0; off >>= 1) {
#pragma unroll
        for (int h = 0; h < NHEAD; h++) sc[h] += __shfl_down(sc[h], off, 64);
    }
    if (c == 0) {
#pragma unroll
        for (int h = 0; h < NHEAD; h++) {
            score[e * 4 + h] = sc[h];
            atomicMax(&smax[d * 4 + h], fenc(sc[h]));
        }
    }
}

// ---- pass 2: softmax denominator ----
__global__ __launch_bounds__(256) void edge_denom_k(
    const float* __restrict__ score, const int* __restrict__ dst_idx,
    const int* __restrict__ smax, float* __restrict__ denom)
{
    int e = blockIdx.x * 256 + threadIdx.x;
    if (e >= E) return;
    int d = dst_idx[e];
#pragma unroll
    for (int h = 0; h < NHEAD; h++) {
        float ex = expf(score[e * 4 + h] - fdec(smax[d * 4 + h]));
        atomicAdd(&denom[d * 4 + h], ex);
    }
}

// ---- pass 3: alpha-weighted aggregation, mean over heads folded in ----
__global__ __launch_bounds__(256) void edge_aggr_k(
    const float* __restrict__ xl, const float* __restrict__ score,
    const int* __restrict__ smax, const float* __restrict__ denom,
    const int* __restrict__ src_idx, const int* __restrict__ dst_idx,
    float* __restrict__ acc)
{
    int e = blockIdx.x * 4 + (threadIdx.x >> 6);
    int c = threadIdx.x & 63;
    if (e >= E) return;
    int s = src_idx[e], d = dst_idx[e];
    float val = 0.f;
#pragma unroll
    for (int h = 0; h < NHEAD; h++) {
        float alpha = expf(score[e * 4 + h] - fdec(smax[d * 4 + h])) /
                      (denom[d * 4 + h] + 1e-16f);
        val += alpha * xl[s * HH + h * HID + c];
    }
    atomicAdd(&acc[d * HID + c], 0.25f * val);
}

// ---- finalize: h = relu(acc + bias) ----
__global__ __launch_bounds__(256) void node_finalize_k(
    const float* __restrict__ acc, const float* __restrict__ bias,
    float* __restrict__ hout)
{
    int i = blockIdx.x * 256 + threadIdx.x;
    if (i >= N * HID) return;
    float v = acc[i] + bias[i & 63];
    hout[i] = (v > 0.f) ? v : 0.f;
}

// ---- pooling + MLP head: one block (64 threads) per graph ----
__global__ __launch_bounds__(64) void pool_head_k(
    const float* __restrict__ h, const int* __restrict__ batch,
    const float* __restrict__ W_fc, const float* __restrict__ b_fc,
    const float* __restrict__ W_res, const float* __restrict__ b_res,
    const float* __restrict__ W_time, const float* __restrict__ b_time,
    float* __restrict__ out)
{
    int g = blockIdx.x;
    int c = threadIdx.x;
    // batch is sorted: binary search [start, end)
    int lo = 0, hi = N;
    while (lo < hi) { int mid = (lo + hi) >> 1; if (batch[mid] < g) lo = mid + 1; else hi = mid; }
    int start = lo;
    hi = N;
    while (lo < hi) { int mid = (lo + hi) >> 1; if (batch[mid] < g + 1) lo = mid + 1; else hi = mid; }
    int end = lo;
    float sum = 0.f;
    for (int n = start; n < end; n++) sum += h[n * HID + c];
    float cnt = (float)(end - start);
    float pooled = sum / fmaxf(cnt, 1.0f);
    __shared__ float ps[HID];
    ps[c] = pooled;
    __syncthreads();
    float gv = b_fc[c];
    for (int k = 0; k < HID; k++) gv += ps[k] * W_fc[k * HID + c];
    gv = fmaxf(gv, 0.f);
    float r = gv * W_res[c];
    float t = gv * W_time[c];
#pragma unroll
    for (int off = 32; off > 0; off >>= 1) {
        r += __shfl_down(r, off, 64);
        t += __shfl_down(t, off, 64);
    }
    if (c == 0) {
        out[g * 2 + 0] = r + b_res[0];
        out[g * 2 + 1] = t + b_time[0];
    }
}

} // namespace

extern "C" void kernel_launch(void* const* d_in, const int* in_sizes, int n_in,
                              void* d_out, int out_size, void* d_ws, size_t ws_size,
                              hipStream_t stream) {
    const float* x         = (const float*)d_in[0];
    const float* edge_attr = (const float*)d_in[1];
    const int*   edge_index= (const int*)d_in[2];
    const int*   batch     = (const int*)d_in[3];
    const float* W_et = (const float*)d_in[4];
    const float* b_et = (const float*)d_in[5];
    const float* W_uw = (const float*)d_in[6];
    const float* b_uw = (const float*)d_in[7];
    const float* W_ua = (const float*)d_in[8];
    const float* b_ua = (const float*)d_in[9];
    const float* Wl0  = (const float*)d_in[10];
    const float* bl0  = (const float*)d_in[11];
    const float* Wr0  = (const float*)d_in[12];
    const float* br0  = (const float*)d_in[13];
    const float* att0 = (const float*)d_in[14];
    const float* We0  = (const float*)d_in[15];
    const float* bias0= (const float*)d_in[16];
    const float* Wl1  = (const float*)d_in[17];
    const float* bl1  = (const float*)d_in[18];
    const float* Wr1  = (const float*)d_in[19];
    const float* br1  = (const float*)d_in[20];
    const float* att1 = (const float*)d_in[21];
    const float* We1  = (const float*)d_in[22];
    const float* bias1= (const float*)d_in[23];
    const float* W_fc = (const float*)d_in[24];
    const float* b_fc = (const float*)d_in[25];
    const float* W_res= (const float*)d_in[26];
    const float* b_res= (const float*)d_in[27];
    const float* W_time=(const float*)d_in[28];
    const float* b_time=(const float*)d_in[29];

    const int* src = edge_index;     // row 0
    const int* dst = edge_index + E; // row 1

    // workspace layout (floats)
    float* ws    = (float*)d_ws;
    float* eap   = ws;                    // E*4
    float* xl    = eap   + (size_t)E * 4; // N*HH
    float* xr    = xl    + (size_t)N * HH;
    float* score = xr    + (size_t)N * HH;   // E*4
    int*   smax  = (int*)(score + (size_t)E * 4); // N*4
    float* denom = (float*)smax + (size_t)N * 4;  // N*4
    float* acc   = denom + (size_t)N * 4;         // N*HID
    float* h1    = acc   + (size_t)N * HID;       // N*HID
    float* h2    = h1    + (size_t)N * HID;       // N*HID

    dim3 b256(256);

    // edge attr projection (shared by both layers)
    edge_feat_k<<<(E + 255) / 256, b256, 0, stream>>>(
        edge_attr, W_et, b_et, W_uw, b_uw, W_ua, b_ua, eap);

    // ---------- layer 0 ----------
    node_proj_k<128><<<(N + 7) / 8, b256, 0, stream>>>(x, Wl0, bl0, Wr0, br0, xl, xr);
    init_layer_k<<<(N * HID + 255) / 256, b256, 0, stream>>>(smax, denom, acc);
    edge_score_k<<<(E + 3) / 4, b256, 0, stream>>>(xl, xr, eap, We0, att0, src, dst, score, smax);
    edge_denom_k<<<(E + 255) / 256, b256, 0, stream>>>(score, dst, smax, denom);
    edge_aggr_k<<<(E + 3) / 4, b256, 0, stream>>>(xl, score, smax, denom, src, dst, acc);
    node_finalize_k<<<(N * HID + 255) / 256, b256, 0, stream>>>(acc, bias0, h1);

    // ---------- layer 1 ----------
    node_proj_k<64><<<(N + 7) / 8, b256, 0, stream>>>(h1, Wl1, bl1, Wr1, br1, xl, xr);
    init_layer_k<<<(N * HID + 255) / 256, b256, 0, stream>>>(smax, denom, acc);
    edge_score_k<<<(E + 3) / 4, b256, 0, stream>>>(xl, xr, eap, We1, att1, src, dst, score, smax);
    edge_denom_k<<<(E + 255) / 256, b256, 0, stream>>>(score, dst, smax, denom);
    edge_aggr_k<<<(E + 3) / 4, b256, 0, stream>>>(xl, score, smax, denom, src, dst, acc);
    node_finalize_k<<<(N * HID + 255) / 256, b256, 0, stream>>>(acc, bias1, h2);

    // ---------- pooling + head ----------
    pool_head_k<<<G, dim3(64), 0, stream>>>(
        h2, batch, W_fc, b_fc, W_res, b_res, W_time, b_time, (float*)d_out);
}

// Round 2
// 1049.904 us; speedup vs baseline: 1.2058x; 1.2058x over previous
//
#include <hip/hip_runtime.h>
#include <math.h>

namespace {

constexpr int N = 50000;
constexpr int E = 400000;
constexpr int G = 64;
constexpr int HID = 64;
constexpr int NHEAD = 4;
constexpr int HH = NHEAD * HID; // 256
constexpr float NEG = 0.2f;

__device__ __forceinline__ int fenc(float f) {
    int i = __float_as_int(f);
    return (i >= 0) ? i : (i ^ 0x7FFFFFFF);
}
__device__ __forceinline__ float fdec(int i) {
    return __int_as_float((i >= 0) ? i : (i ^ 0x7FFFFFFF));
}

// ---- edge attr projection: eap[e][4] ----
__global__ __launch_bounds__(256) void edge_feat_k(
    const float* __restrict__ ea,
    const float* __restrict__ W_et, const float* __restrict__ b_et,
    const float* __restrict__ W_uw, const float* __restrict__ b_uw,
    const float* __restrict__ W_ua, const float* __restrict__ b_ua,
    float* __restrict__ eap)
{
    int e = blockIdx.x * 256 + threadIdx.x;
    if (e >= E) return;
    float et = ea[e * 2 + 0], uw = ea[e * 2 + 1];
    float ua = 1.f / (1.f + expf(-(uw * W_ua[0] + b_ua[0])));
    eap[e * 4 + 0] = et * W_et[0] + b_et[0];
    eap[e * 4 + 1] = et * W_et[1] + b_et[1];
    eap[e * 4 + 2] = (uw * W_uw[0] + b_uw[0]) * ua;
    eap[e * 4 + 3] = (uw * W_uw[1] + b_uw[1]) * ua;
}

// ---- node projections: xl = x@Wl+bl, xr = x@Wr+br, (N x HH) ----
template <int IC>
__global__ __launch_bounds__(256) void node_proj_k(
    const float* __restrict__ x,
    const float* __restrict__ Wl, const float* __restrict__ bl,
    const float* __restrict__ Wr, const float* __restrict__ br,
    float* __restrict__ xl, float* __restrict__ xr)
{
    constexpr int NPB = 8;
    __shared__ float xs[NPB][IC];
    const int base = blockIdx.x * NPB;
    const int tid = threadIdx.x;
    for (int idx = tid; idx < NPB * IC; idx += 256) {
        int j = idx / IC, k = idx - j * IC;
        int n = base + j;
        xs[j][k] = (n < N) ? x[n * IC + k] : 0.f;
    }
    __syncthreads();
    float accl[NPB], accr[NPB];
#pragma unroll
    for (int j = 0; j < NPB; j++) { accl[j] = 0.f; accr[j] = 0.f; }
    for (int k = 0; k < IC; k++) {
        float wl = Wl[k * HH + tid];
        float wr = Wr[k * HH + tid];
#pragma unroll
        for (int j = 0; j < NPB; j++) {
            accl[j] += xs[j][k] * wl;
            accr[j] += xs[j][k] * wr;
        }
    }
    float bll = bl[tid], brr = br[tid];
#pragma unroll
    for (int j = 0; j < NPB; j++) {
        int n = base + j;
        if (n < N) {
            xl[n * HH + tid] = accl[j] + bll;
            xr[n * HH + tid] = accr[j] + brr;
        }
    }
}

// ---- per-layer init: smax = -inf(enc), denom = 0, acc = 0, pooled = 0 ----
__global__ __launch_bounds__(256) void init_layer_k(
    int* __restrict__ smax, float* __restrict__ denom, float* __restrict__ acc,
    float* __restrict__ pooled)
{
    int i = blockIdx.x * 256 + threadIdx.x;
    if (i < N * NHEAD) { smax[i] = 0x80000000; denom[i] = 0.f; }
    if (i < N * HID) acc[i] = 0.f;
    if (i < G * HID) pooled[i] = 0.f;
}

// ---- pass 1: scores + segment max (one 64-lane wave per edge, float4 loads) ----
__global__ __launch_bounds__(256) void edge_score_k(
    const float* __restrict__ xl, const float* __restrict__ xr,
    const float* __restrict__ eap, const float* __restrict__ We,
    const float* __restrict__ att,
    const int* __restrict__ src_idx, const int* __restrict__ dst_idx,
    float* __restrict__ score, int* __restrict__ smax)
{
    int e = blockIdx.x * 4 + (threadIdx.x >> 6);
    int c = threadIdx.x & 63;   // lane; covers cols c*4 .. c*4+3, head h = c>>4
    if (e >= E) return;
    int s = src_idx[e], d = dst_idx[e];
    float a0 = eap[e * 4 + 0], a1 = eap[e * 4 + 1];
    float a2 = eap[e * 4 + 2], a3 = eap[e * 4 + 3];
    int c4 = c * 4;
    float4 vl = *(const float4*)&xl[s * HH + c4];
    float4 vr = *(const float4*)&xr[d * HH + c4];
    float4 w0 = *(const float4*)&We[0 * HH + c4];
    float4 w1 = *(const float4*)&We[1 * HH + c4];
    float4 w2 = *(const float4*)&We[2 * HH + c4];
    float4 w3 = *(const float4*)&We[3 * HH + c4];
    float4 av = *(const float4*)&att[c4];
    float partial;
    {
        float m0 = vl.x + vr.x + a0 * w0.x + a1 * w1.x + a2 * w2.x + a3 * w3.x;
        float m1 = vl.y + vr.y + a0 * w0.y + a1 * w1.y + a2 * w2.y + a3 * w3.y;
        float m2 = vl.z + vr.z + a0 * w0.z + a1 * w1.z + a2 * w2.z + a3 * w3.z;
        float m3 = vl.w + vr.w + a0 * w0.w + a1 * w1.w + a2 * w2.w + a3 * w3.w;
        m0 = (m0 > 0.f) ? m0 : NEG * m0;
        m1 = (m1 > 0.f) ? m1 : NEG * m1;
        m2 = (m2 > 0.f) ? m2 : NEG * m2;
        m3 = (m3 > 0.f) ? m3 : NEG * m3;
        partial = m0 * av.x + m1 * av.y + m2 * av.z + m3 * av.w;
    }
    // reduce within each 16-lane group (one head per group)
#pragma unroll
    for (int off = 8; off > 0; off >>= 1)
        partial += __shfl_xor(partial, off, 64);
    if ((c & 15) == 0) {
        int h = c >> 4;
        score[e * 4 + h] = partial;
        atomicMax(&smax[d * 4 + h], fenc(partial));
    }
}

// ---- pass 2: softmax denominator ----
__global__ __launch_bounds__(256) void edge_denom_k(
    const float* __restrict__ score, const int* __restrict__ dst_idx,
    const int* __restrict__ smax, float* __restrict__ denom)
{
    int e = blockIdx.x * 256 + threadIdx.x;
    if (e >= E) return;
    int d = dst_idx[e];
#pragma unroll
    for (int h = 0; h < NHEAD; h++) {
        float ex = expf(score[e * 4 + h] - fdec(smax[d * 4 + h]));
        atomicAdd(&denom[d * 4 + h], ex);
    }
}

// ---- pass 3: alpha-weighted aggregation, mean over heads folded in ----
__global__ __launch_bounds__(256) void edge_aggr_k(
    const float* __restrict__ xl, const float* __restrict__ score,
    const int* __restrict__ smax, const float* __restrict__ denom,
    const int* __restrict__ src_idx, const int* __restrict__ dst_idx,
    float* __restrict__ acc)
{
    int e = blockIdx.x * 4 + (threadIdx.x >> 6);
    int c = threadIdx.x & 63;
    if (e >= E) return;
    int s = src_idx[e], d = dst_idx[e];
    float val = 0.f;
#pragma unroll
    for (int h = 0; h < NHEAD; h++) {
        float alpha = expf(score[e * 4 + h] - fdec(smax[d * 4 + h])) /
                      (denom[d * 4 + h] + 1e-16f);
        val += alpha * xl[s * HH + h * HID + c];
    }
    atomicAdd(&acc[d * HID + c], 0.25f * val);
}

// ---- finalize: h = relu(acc + bias) ----
__global__ __launch_bounds__(256) void node_finalize_k(
    const float* __restrict__ acc, const float* __restrict__ bias,
    float* __restrict__ hout)
{
    int i = blockIdx.x * 256 + threadIdx.x;
    if (i >= N * HID) return;
    float v = acc[i] + bias[i & 63];
    hout[i] = (v > 0.f) ? v : 0.f;
}

// ---- pooling stage 1: atomic segment sum over nodes ----
__global__ __launch_bounds__(256) void pool_atomic_k(
    const float* __restrict__ h, const int* __restrict__ batch,
    float* __restrict__ pooled)
{
    int i = blockIdx.x * 256 + threadIdx.x;
    if (i >= N * HID) return;
    int n = i >> 6, c = i & 63;
    atomicAdd(&pooled[batch[n] * HID + c], h[i]);
}

// ---- pooling stage 2 + MLP head: one block (64 threads) per graph ----
__global__ __launch_bounds__(64) void head_k(
    const float* __restrict__ pooled, const int* __restrict__ batch,
    const float* __restrict__ W_fc, const float* __restrict__ b_fc,
    const float* __restrict__ W_res, const float* __restrict__ b_res,
    const float* __restrict__ W_time, const float* __restrict__ b_time,
    float* __restrict__ out)
{
    int g = blockIdx.x;
    int c = threadIdx.x;
    // batch is sorted: binary search for count of nodes in graph g
    int lo = 0, hi = N;
    while (lo < hi) { int mid = (lo + hi) >> 1; if (batch[mid] < g) lo = mid + 1; else hi = mid; }
    int start = lo;
    hi = N;
    while (lo < hi) { int mid = (lo + hi) >> 1; if (batch[mid] < g + 1) lo = mid + 1; else hi = mid; }
    int end = lo;
    float cnt = (float)(end - start);
    float p = pooled[g * HID + c] / fmaxf(cnt, 1.0f);
    __shared__ float ps[HID];
    ps[c] = p;
    __syncthreads();
    float gv = b_fc[c];
    for (int k = 0; k < HID; k++) gv += ps[k] * W_fc[k * HID + c];
    gv = fmaxf(gv, 0.f);
    float r = gv * W_res[c];
    float t = gv * W_time[c];
#pragma unroll
    for (int off = 32; off > 0; off >>= 1) {
        r += __shfl_down(r, off, 64);
        t += __shfl_down(t, off, 64);
    }
    if (c == 0) {
        out[g * 2 + 0] = r + b_res[0];
        out[g * 2 + 1] = t + b_time[0];
    }
}

} // namespace

extern "C" void kernel_launch(void* const* d_in, const int* in_sizes, int n_in,
                              void* d_out, int out_size, void* d_ws, size_t ws_size,
                              hipStream_t stream) {
    const float* x         = (const float*)d_in[0];
    const float* edge_attr = (const float*)d_in[1];
    const int*   edge_index= (const int*)d_in[2];
    const int*   batch     = (const int*)d_in[3];
    const float* W_et = (const float*)d_in[4];
    const float* b_et = (const float*)d_in[5];
    const float* W_uw = (const float*)d_in[6];
    const float* b_uw = (const float*)d_in[7];
    const float* W_ua = (const float*)d_in[8];
    const float* b_ua = (const float*)d_in[9];
    const float* Wl0  = (const float*)d_in[10];
    const float* bl0  = (const float*)d_in[11];
    const float* Wr0  = (const float*)d_in[12];
    const float* br0  = (const float*)d_in[13];
    const float* att0 = (const float*)d_in[14];
    const float* We0  = (const float*)d_in[15];
    const float* bias0= (const float*)d_in[16];
    const float* Wl1  = (const float*)d_in[17];
    const float* bl1  = (const float*)d_in[18];
    const float* Wr1  = (const float*)d_in[19];
    const float* br1  = (const float*)d_in[20];
    const float* att1 = (const float*)d_in[21];
    const float* We1  = (const float*)d_in[22];
    const float* bias1= (const float*)d_in[23];
    const float* W_fc = (const float*)d_in[24];
    const float* b_fc = (const float*)d_in[25];
    const float* W_res= (const float*)d_in[26];
    const float* b_res= (const float*)d_in[27];
    const float* W_time=(const float*)d_in[28];
    const float* b_time=(const float*)d_in[29];

    const int* src = edge_index;     // row 0
    const int* dst = edge_index + E; // row 1

    // workspace layout (floats)
    float* ws    = (float*)d_ws;
    float* eap   = ws;                    // E*4
    float* xl    = eap   + (size_t)E * 4; // N*HH
    float* xr    = xl    + (size_t)N * HH;
    float* score = xr    + (size_t)N * HH;   // E*4
    int*   smax  = (int*)(score + (size_t)E * 4); // N*4
    float* denom = (float*)smax + (size_t)N * 4;  // N*4
    float* acc   = denom + (size_t)N * 4;         // N*HID
    float* h1    = acc   + (size_t)N * HID;       // N*HID
    float* h2    = h1    + (size_t)N * HID;       // N*HID
    float* pooled= h2    + (size_t)N * HID;       // G*HID

    dim3 b256(256);

    // edge attr projection (shared by both layers)
    edge_feat_k<<<(E + 255) / 256, b256, 0, stream>>>(
        edge_attr, W_et, b_et, W_uw, b_uw, W_ua, b_ua, eap);

    // ---------- layer 0 ----------
    node_proj_k<128><<<(N + 7) / 8, b256, 0, stream>>>(x, Wl0, bl0, Wr0, br0, xl, xr);
    init_layer_k<<<(N * HID + 255) / 256, b256, 0, stream>>>(smax, denom, acc, pooled);
    edge_score_k<<<(E + 3) / 4, b256, 0, stream>>>(xl, xr, eap, We0, att0, src, dst, score, smax);
    edge_denom_k<<<(E + 255) / 256, b256, 0, stream>>>(score, dst, smax, denom);
    edge_aggr_k<<<(E + 3) / 4, b256, 0, stream>>>(xl, score, smax, denom, src, dst, acc);
    node_finalize_k<<<(N * HID + 255) / 256, b256, 0, stream>>>(acc, bias0, h1);

    // ---------- layer 1 ----------
    node_proj_k<64><<<(N + 7) / 8, b256, 0, stream>>>(h1, Wl1, bl1, Wr1, br1, xl, xr);
    init_layer_k<<<(N * HID + 255) / 256, b256, 0, stream>>>(smax, denom, acc, pooled);
    edge_score_k<<<(E + 3) / 4, b256, 0, stream>>>(xl, xr, eap, We1, att1, src, dst, score, smax);
    edge_denom_k<<<(E + 255) / 256, b256, 0, stream>>>(score, dst, smax, denom);
    edge_aggr_k<<<(E + 3) / 4, b256, 0, stream>>>(xl, score, smax, denom, src, dst, acc);
    node_finalize_k<<<(N * HID + 255) / 256, b256, 0, stream>>>(acc, bias1, h2);

    // ---------- pooling + head ----------
    pool_atomic_k<<<(N * HID + 255) / 256, b256, 0, stream>>>(h2, batch, pooled);
    head_k<<<G, dim3(64), 0, stream>>>(
        pooled, batch, W_fc, b_fc, W_res, b_res, W_time, b_time, (float*)d_out);
}

// Round 3
// 552.442 us; speedup vs baseline: 2.2915x; 1.9005x over previous
//
#include <hip/hip_runtime.h>
#include <math.h>

namespace {

constexpr int N = 50000;
constexpr int E = 400000;
constexpr int G = 64;
constexpr int HID = 64;
constexpr int HH = 256; // NHEAD*HID
constexpr float NEG = 0.2f;

// ---- edge attr projection: eap[e][4]; also zeroes deg[] ----
__global__ __launch_bounds__(256) void edge_feat_k(
    const float* __restrict__ ea,
    const float* __restrict__ W_et, const float* __restrict__ b_et,
    const float* __restrict__ W_uw, const float* __restrict__ b_uw,
    const float* __restrict__ W_ua, const float* __restrict__ b_ua,
    float* __restrict__ eap, int* __restrict__ deg)
{
    int e = blockIdx.x * 256 + threadIdx.x;
    if (e < N) deg[e] = 0;
    if (e >= E) return;
    float et = ea[e * 2 + 0], uw = ea[e * 2 + 1];
    float ua = 1.f / (1.f + expf(-(uw * W_ua[0] + b_ua[0])));
    float4 v;
    v.x = et * W_et[0] + b_et[0];
    v.y = et * W_et[1] + b_et[1];
    v.z = (uw * W_uw[0] + b_uw[0]) * ua;
    v.w = (uw * W_uw[1] + b_uw[1]) * ua;
    *(float4*)&eap[e * 4] = v;
}

// ---- CSR build ----
__global__ __launch_bounds__(256) void hist_k(
    const int* __restrict__ dst, int* __restrict__ deg)
{
    int e = blockIdx.x * 256 + threadIdx.x;
    if (e < E) atomicAdd(&deg[dst[e]], 1);
}

__global__ __launch_bounds__(256) void scan1_k(
    const int* __restrict__ deg, int* __restrict__ pre, int* __restrict__ bsum)
{
    __shared__ int s[256];
    int i = blockIdx.x * 256 + threadIdx.x;
    int v = (i < N) ? deg[i] : 0;
    s[threadIdx.x] = v;
    __syncthreads();
    for (int off = 1; off < 256; off <<= 1) {
        int t = (threadIdx.x >= off) ? s[threadIdx.x - off] : 0;
        __syncthreads();
        s[threadIdx.x] += t;
        __syncthreads();
    }
    if (i < N) pre[i] = s[threadIdx.x] - v; // exclusive within block
    if (threadIdx.x == 255) bsum[blockIdx.x] = s[255];
}

__global__ __launch_bounds__(256) void scan2_k(
    int* __restrict__ bsum, int nb, float* __restrict__ pooled)
{
    __shared__ int s[256];
    int tid = threadIdx.x;
    int v = (tid < nb) ? bsum[tid] : 0;
    s[tid] = v;
    __syncthreads();
    for (int off = 1; off < 256; off <<= 1) {
        int t = (tid >= off) ? s[tid - off] : 0;
        __syncthreads();
        s[tid] += t;
        __syncthreads();
    }
    if (tid < nb) bsum[tid] = s[tid] - v; // exclusive block prefix (in place)
    for (int i = tid; i < G * HID; i += 256) pooled[i] = 0.f;
}

__global__ __launch_bounds__(256) void scan3_k(
    int* __restrict__ pre, const int* __restrict__ bsum, int* __restrict__ cursor)
{
    int i = blockIdx.x * 256 + threadIdx.x;
    if (i >= N) return;
    int r = pre[i] + bsum[blockIdx.x];
    pre[i] = r;       // row_start
    cursor[i] = r;
}

__global__ __launch_bounds__(256) void scatter_k(
    const int* __restrict__ src, const int* __restrict__ dst,
    int* __restrict__ cursor, int* __restrict__ csr_src, int* __restrict__ csr_eid)
{
    int e = blockIdx.x * 256 + threadIdx.x;
    if (e >= E) return;
    int pos = atomicAdd(&cursor[dst[e]], 1);
    csr_src[pos] = src[e];
    csr_eid[pos] = e;
}

// ---- node projections: xl = x@Wl+bl, xr = x@Wr+br, (N x HH) ----
template <int IC>
__global__ __launch_bounds__(256) void node_proj_k(
    const float* __restrict__ x,
    const float* __restrict__ Wl, const float* __restrict__ bl,
    const float* __restrict__ Wr, const float* __restrict__ br,
    float* __restrict__ xl, float* __restrict__ xr)
{
    constexpr int NPB = 16;
    __shared__ float xs[NPB][IC];
    const int base = blockIdx.x * NPB;
    const int tid = threadIdx.x;
    for (int idx = tid; idx < NPB * IC / 4; idx += 256) {
        int j = idx / (IC / 4), k4 = idx - j * (IC / 4);
        int n = base + j;
        float4 v = make_float4(0.f, 0.f, 0.f, 0.f);
        if (n < N) v = *(const float4*)&x[n * IC + k4 * 4];
        *(float4*)&xs[j][k4 * 4] = v;
    }
    __syncthreads();
    float accl[NPB], accr[NPB];
#pragma unroll
    for (int j = 0; j < NPB; j++) { accl[j] = 0.f; accr[j] = 0.f; }
    for (int k = 0; k < IC; k += 4) {
        float wl0 = Wl[(k + 0) * HH + tid];
        float wl1 = Wl[(k + 1) * HH + tid];
        float wl2 = Wl[(k + 2) * HH + tid];
        float wl3 = Wl[(k + 3) * HH + tid];
        float wr0 = Wr[(k + 0) * HH + tid];
        float wr1 = Wr[(k + 1) * HH + tid];
        float wr2 = Wr[(k + 2) * HH + tid];
        float wr3 = Wr[(k + 3) * HH + tid];
#pragma unroll
        for (int j = 0; j < NPB; j++) {
            float4 xv = *(const float4*)&xs[j][k];
            accl[j] += xv.x * wl0 + xv.y * wl1 + xv.z * wl2 + xv.w * wl3;
            accr[j] += xv.x * wr0 + xv.y * wr1 + xv.z * wr2 + xv.w * wr3;
        }
    }
    float bll = bl[tid], brr = br[tid];
#pragma unroll
    for (int j = 0; j < NPB; j++) {
        int n = base + j;
        if (n < N) {
            xl[n * HH + tid] = accl[j] + bll;
            xr[n * HH + tid] = accr[j] + brr;
        }
    }
}

// ---- fused GAT layer: score + online softmax + aggregate + mean + bias + relu ----
// one 64-lane wave per dst node; lane l covers cols 4l..4l+3 (head = l>>4)
__global__ __launch_bounds__(256) void gat_aggr_k(
    const float* __restrict__ xl, const float* __restrict__ xr,
    const float* __restrict__ eap, const float* __restrict__ We,
    const float* __restrict__ att,
    const int* __restrict__ row_start, const int* __restrict__ deg,
    const int* __restrict__ csr_src, const int* __restrict__ csr_eid,
    const float* __restrict__ bias, float* __restrict__ hout)
{
    int d = blockIdx.x * 4 + (threadIdx.x >> 6);
    int lane = threadIdx.x & 63;
    if (d >= N) return;
    int c4 = lane * 4;
    const float4 w0 = *(const float4*)&We[0 * HH + c4];
    const float4 w1 = *(const float4*)&We[1 * HH + c4];
    const float4 w2 = *(const float4*)&We[2 * HH + c4];
    const float4 w3 = *(const float4*)&We[3 * HH + c4];
    const float4 av = *(const float4*)&att[c4];
    const float4 vr = *(const float4*)&xr[(size_t)d * HH + c4];
    int start = row_start[d];
    int cnt = deg[d];
    float m = -INFINITY, denom = 0.f;
    float ax = 0.f, ay = 0.f, az = 0.f, aw = 0.f;
    for (int idx = start; idx < start + cnt; ++idx) {
        int s = csr_src[idx];
        int e = csr_eid[idx];
        float4 a = *(const float4*)&eap[e * 4];
        float4 vl = *(const float4*)&xl[(size_t)s * HH + c4];
        float q0 = vl.x + vr.x + a.x * w0.x + a.y * w1.x + a.z * w2.x + a.w * w3.x;
        float q1 = vl.y + vr.y + a.x * w0.y + a.y * w1.y + a.z * w2.y + a.w * w3.y;
        float q2 = vl.z + vr.z + a.x * w0.z + a.y * w1.z + a.z * w2.z + a.w * w3.z;
        float q3 = vl.w + vr.w + a.x * w0.w + a.y * w1.w + a.z * w2.w + a.w * w3.w;
        q0 = (q0 > 0.f) ? q0 : NEG * q0;
        q1 = (q1 > 0.f) ? q1 : NEG * q1;
        q2 = (q2 > 0.f) ? q2 : NEG * q2;
        q3 = (q3 > 0.f) ? q3 : NEG * q3;
        float p = q0 * av.x + q1 * av.y + q2 * av.z + q3 * av.w;
        // reduce within 16-lane group (one head per group)
        p += __shfl_xor(p, 1, 64);
        p += __shfl_xor(p, 2, 64);
        p += __shfl_xor(p, 4, 64);
        p += __shfl_xor(p, 8, 64);
        // online softmax update (branchless)
        float newm = fmaxf(m, p);
        float so = expf(m - newm);   // 0 on first edge (m=-inf)
        float ex = expf(p - newm);
        denom = denom * so + ex;
        ax = ax * so + ex * vl.x;
        ay = ay * so + ex * vl.y;
        az = az * so + ex * vl.z;
        aw = aw * so + ex * vl.w;
        m = newm;
    }
    float inv = 1.f / (denom + 1e-16f);
    ax *= inv; ay *= inv; az *= inv; aw *= inv;
    // sum over the 4 heads (groups 16 apart)
    ax += __shfl_xor(ax, 16, 64); ax += __shfl_xor(ax, 32, 64);
    ay += __shfl_xor(ay, 16, 64); ay += __shfl_xor(ay, 32, 64);
    az += __shfl_xor(az, 16, 64); az += __shfl_xor(az, 32, 64);
    aw += __shfl_xor(aw, 16, 64); aw += __shfl_xor(aw, 32, 64);
    if (lane < 16) {
        float4 b = *(const float4*)&bias[c4];
        float4 o;
        o.x = fmaxf(0.25f * ax + b.x, 0.f);
        o.y = fmaxf(0.25f * ay + b.y, 0.f);
        o.z = fmaxf(0.25f * az + b.z, 0.f);
        o.w = fmaxf(0.25f * aw + b.w, 0.f);
        *(float4*)&hout[(size_t)d * HID + c4] = o;
    }
}

// ---- pooling: chunked segment sum (batch is sorted) ----
__global__ __launch_bounds__(256) void pool_k(
    const float* __restrict__ h, const int* __restrict__ batch,
    float* __restrict__ pooled)
{
    constexpr int CH = 16;
    int c = threadIdx.x & 63;
    int chunk = blockIdx.x * 4 + (threadIdx.x >> 6);
    int n0 = chunk * CH;
    if (n0 >= N) return;
    int nend = (n0 + CH < N) ? n0 + CH : N;
    float sum = 0.f;
    int curb = batch[n0];
    for (int n = n0; n < nend; ++n) {
        int b = batch[n];
        if (b != curb) {
            atomicAdd(&pooled[curb * HID + c], sum);
            sum = 0.f; curb = b;
        }
        sum += h[(size_t)n * HID + c];
    }
    atomicAdd(&pooled[curb * HID + c], sum);
}

// ---- MLP head: one block (64 threads) per graph ----
__global__ __launch_bounds__(64) void head_k(
    const float* __restrict__ pooled, const int* __restrict__ batch,
    const float* __restrict__ W_fc, const float* __restrict__ b_fc,
    const float* __restrict__ W_res, const float* __restrict__ b_res,
    const float* __restrict__ W_time, const float* __restrict__ b_time,
    float* __restrict__ out)
{
    int g = blockIdx.x;
    int c = threadIdx.x;
    int lo = 0, hi = N;
    while (lo < hi) { int mid = (lo + hi) >> 1; if (batch[mid] < g) lo = mid + 1; else hi = mid; }
    int start = lo;
    hi = N;
    while (lo < hi) { int mid = (lo + hi) >> 1; if (batch[mid] < g + 1) lo = mid + 1; else hi = mid; }
    int end = lo;
    float cnt = (float)(end - start);
    float p = pooled[g * HID + c] / fmaxf(cnt, 1.0f);
    __shared__ float ps[HID];
    ps[c] = p;
    __syncthreads();
    float gv = b_fc[c];
    for (int k = 0; k < HID; k++) gv += ps[k] * W_fc[k * HID + c];
    gv = fmaxf(gv, 0.f);
    float r = gv * W_res[c];
    float t = gv * W_time[c];
#pragma unroll
    for (int off = 32; off > 0; off >>= 1) {
        r += __shfl_down(r, off, 64);
        t += __shfl_down(t, off, 64);
    }
    if (c == 0) {
        out[g * 2 + 0] = r + b_res[0];
        out[g * 2 + 1] = t + b_time[0];
    }
}

} // namespace

extern "C" void kernel_launch(void* const* d_in, const int* in_sizes, int n_in,
                              void* d_out, int out_size, void* d_ws, size_t ws_size,
                              hipStream_t stream) {
    const float* x         = (const float*)d_in[0];
    const float* edge_attr = (const float*)d_in[1];
    const int*   edge_index= (const int*)d_in[2];
    const int*   batch     = (const int*)d_in[3];
    const float* W_et = (const float*)d_in[4];
    const float* b_et = (const float*)d_in[5];
    const float* W_uw = (const float*)d_in[6];
    const float* b_uw = (const float*)d_in[7];
    const float* W_ua = (const float*)d_in[8];
    const float* b_ua = (const float*)d_in[9];
    const float* Wl0  = (const float*)d_in[10];
    const float* bl0  = (const float*)d_in[11];
    const float* Wr0  = (const float*)d_in[12];
    const float* br0  = (const float*)d_in[13];
    const float* att0 = (const float*)d_in[14];
    const float* We0  = (const float*)d_in[15];
    const float* bias0= (const float*)d_in[16];
    const float* Wl1  = (const float*)d_in[17];
    const float* bl1  = (const float*)d_in[18];
    const float* Wr1  = (const float*)d_in[19];
    const float* br1  = (const float*)d_in[20];
    const float* att1 = (const float*)d_in[21];
    const float* We1  = (const float*)d_in[22];
    const float* bias1= (const float*)d_in[23];
    const float* W_fc = (const float*)d_in[24];
    const float* b_fc = (const float*)d_in[25];
    const float* W_res= (const float*)d_in[26];
    const float* b_res= (const float*)d_in[27];
    const float* W_time=(const float*)d_in[28];
    const float* b_time=(const float*)d_in[29];

    const int* src = edge_index;     // row 0
    const int* dst = edge_index + E; // row 1

    // workspace layout
    float* ws    = (float*)d_ws;
    float* eap   = ws;                        // E*4
    float* xl    = eap + (size_t)E * 4;       // N*HH
    float* xr    = xl  + (size_t)N * HH;      // N*HH
    float* h1    = xr  + (size_t)N * HH;      // N*HID
    float* h2    = h1  + (size_t)N * HID;     // N*HID
    float* pooled= h2  + (size_t)N * HID;     // G*HID
    int*   deg      = (int*)(pooled + (size_t)G * HID); // N
    int*   row_start= deg + N;                // N
    int*   cursor   = row_start + N;          // N
    int*   bsum     = cursor + N;             // 256
    int*   csr_src  = bsum + 256;             // E
    int*   csr_eid  = csr_src + E;            // E

    dim3 b256(256);
    const int NB = (N + 255) / 256; // 196

    // edge features + deg=0
    edge_feat_k<<<(E + 255) / 256, b256, 0, stream>>>(
        edge_attr, W_et, b_et, W_uw, b_uw, W_ua, b_ua, eap, deg);
    // CSR build
    hist_k<<<(E + 255) / 256, b256, 0, stream>>>(dst, deg);
    scan1_k<<<NB, b256, 0, stream>>>(deg, row_start, bsum);
    scan2_k<<<1, b256, 0, stream>>>(bsum, NB, pooled);
    scan3_k<<<NB, b256, 0, stream>>>(row_start, bsum, cursor);
    scatter_k<<<(E + 255) / 256, b256, 0, stream>>>(src, dst, cursor, csr_src, csr_eid);

    // ---------- layer 0 ----------
    node_proj_k<128><<<(N + 15) / 16, b256, 0, stream>>>(x, Wl0, bl0, Wr0, br0, xl, xr);
    gat_aggr_k<<<(N + 3) / 4, b256, 0, stream>>>(
        xl, xr, eap, We0, att0, row_start, deg, csr_src, csr_eid, bias0, h1);

    // ---------- layer 1 ----------
    node_proj_k<64><<<(N + 15) / 16, b256, 0, stream>>>(h1, Wl1, bl1, Wr1, br1, xl, xr);
    gat_aggr_k<<<(N + 3) / 4, b256, 0, stream>>>(
        xl, xr, eap, We1, att1, row_start, deg, csr_src, csr_eid, bias1, h2);

    // ---------- pooling + head ----------
    pool_k<<<((N + 15) / 16 + 3) / 4, b256, 0, stream>>>(h2, batch, pooled);
    head_k<<<G, dim3(64), 0, stream>>>(
        pooled, batch, W_fc, b_fc, W_res, b_res, W_time, b_time, (float*)d_out);
}

// Round 4
// 543.748 us; speedup vs baseline: 2.3282x; 1.0160x over previous
//
#include <hip/hip_runtime.h>
#include <math.h>

namespace {

constexpr int N = 50000;
constexpr int E = 400000;
constexpr int G = 64;
constexpr int HID = 64;
constexpr int HH = 256; // NHEAD*HID
constexpr float NEG = 0.2f;

// ---- edge attr projection: eap[e][4]; also zeroes deg[] ----
__global__ __launch_bounds__(256) void edge_feat_k(
    const float* __restrict__ ea,
    const float* __restrict__ W_et, const float* __restrict__ b_et,
    const float* __restrict__ W_uw, const float* __restrict__ b_uw,
    const float* __restrict__ W_ua, const float* __restrict__ b_ua,
    float* __restrict__ eap, int* __restrict__ deg)
{
    int e = blockIdx.x * 256 + threadIdx.x;
    if (e < N) deg[e] = 0;
    if (e >= E) return;
    float et = ea[e * 2 + 0], uw = ea[e * 2 + 1];
    float ua = 1.f / (1.f + expf(-(uw * W_ua[0] + b_ua[0])));
    float4 v;
    v.x = et * W_et[0] + b_et[0];
    v.y = et * W_et[1] + b_et[1];
    v.z = (uw * W_uw[0] + b_uw[0]) * ua;
    v.w = (uw * W_uw[1] + b_uw[1]) * ua;
    *(float4*)&eap[e * 4] = v;
}

// ---- weight pack: Wp[(k>>2)*HH*4 + col*4 + (k&3)] = W[k*HH + col] ----
__global__ __launch_bounds__(256) void pack_w_k(
    const float* __restrict__ W, float* __restrict__ Wp, int IC)
{
    int idx = blockIdx.x * 256 + threadIdx.x;
    if (idx >= IC * HH) return;
    int k = idx / HH, col = idx - k * HH;
    Wp[(k >> 2) * (HH * 4) + col * 4 + (k & 3)] = W[idx];
}

// ---- CSR build ----
__global__ __launch_bounds__(256) void hist_k(
    const int* __restrict__ dst, int* __restrict__ deg)
{
    int e = blockIdx.x * 256 + threadIdx.x;
    if (e < E) atomicAdd(&deg[dst[e]], 1);
}

__global__ __launch_bounds__(256) void scan1_k(
    const int* __restrict__ deg, int* __restrict__ pre, int* __restrict__ bsum)
{
    __shared__ int s[256];
    int i = blockIdx.x * 256 + threadIdx.x;
    int v = (i < N) ? deg[i] : 0;
    s[threadIdx.x] = v;
    __syncthreads();
    for (int off = 1; off < 256; off <<= 1) {
        int t = (threadIdx.x >= off) ? s[threadIdx.x - off] : 0;
        __syncthreads();
        s[threadIdx.x] += t;
        __syncthreads();
    }
    if (i < N) pre[i] = s[threadIdx.x] - v;
    if (threadIdx.x == 255) bsum[blockIdx.x] = s[255];
}

__global__ __launch_bounds__(256) void scan2_k(
    int* __restrict__ bsum, int nb, float* __restrict__ pooled)
{
    __shared__ int s[256];
    int tid = threadIdx.x;
    int v = (tid < nb) ? bsum[tid] : 0;
    s[tid] = v;
    __syncthreads();
    for (int off = 1; off < 256; off <<= 1) {
        int t = (tid >= off) ? s[tid - off] : 0;
        __syncthreads();
        s[tid] += t;
        __syncthreads();
    }
    if (tid < nb) bsum[tid] = s[tid] - v;
    for (int i = tid; i < G * HID; i += 256) pooled[i] = 0.f;
}

__global__ __launch_bounds__(256) void scan3_k(
    int* __restrict__ pre, const int* __restrict__ bsum, int* __restrict__ cursor)
{
    int i = blockIdx.x * 256 + threadIdx.x;
    if (i >= N) return;
    int r = pre[i] + bsum[blockIdx.x];
    pre[i] = r;
    cursor[i] = r;
}

__global__ __launch_bounds__(256) void scatter_k(
    const int* __restrict__ src, const int* __restrict__ dst,
    int* __restrict__ cursor, int* __restrict__ csr_src, int* __restrict__ csr_eid)
{
    int e = blockIdx.x * 256 + threadIdx.x;
    if (e >= E) return;
    int pos = atomicAdd(&cursor[dst[e]], 1);
    csr_src[pos] = src[e];
    csr_eid[pos] = e;
}

// ---- node projections with k-panel packed weights ----
template <int IC>
__global__ __launch_bounds__(256) void node_proj_k(
    const float* __restrict__ x,
    const float* __restrict__ WlT, const float* __restrict__ bl,
    const float* __restrict__ WrT, const float* __restrict__ br,
    float* __restrict__ xl, float* __restrict__ xr)
{
    constexpr int NPB = 16;
    __shared__ float xs[NPB][IC];
    const int base = blockIdx.x * NPB;
    const int tid = threadIdx.x;
    for (int idx = tid; idx < NPB * IC / 4; idx += 256) {
        int j = idx / (IC / 4), k4 = idx - j * (IC / 4);
        int n = base + j;
        float4 v = make_float4(0.f, 0.f, 0.f, 0.f);
        if (n < N) v = *(const float4*)&x[n * IC + k4 * 4];
        *(float4*)&xs[j][k4 * 4] = v;
    }
    __syncthreads();
    float accl[NPB], accr[NPB];
#pragma unroll
    for (int j = 0; j < NPB; j++) { accl[j] = 0.f; accr[j] = 0.f; }
#pragma unroll 2
    for (int k4 = 0; k4 < IC / 4; k4++) {
        float4 wl = *(const float4*)&WlT[k4 * (HH * 4) + tid * 4];
        float4 wr = *(const float4*)&WrT[k4 * (HH * 4) + tid * 4];
#pragma unroll
        for (int j = 0; j < NPB; j++) {
            float4 xv = *(const float4*)&xs[j][k4 * 4];
            accl[j] += xv.x * wl.x + xv.y * wl.y + xv.z * wl.z + xv.w * wl.w;
            accr[j] += xv.x * wr.x + xv.y * wr.y + xv.z * wr.z + xv.w * wr.w;
        }
    }
    float bll = bl[tid], brr = br[tid];
#pragma unroll
    for (int j = 0; j < NPB; j++) {
        int n = base + j;
        if (n < N) {
            xl[n * HH + tid] = accl[j] + bll;
            xr[n * HH + tid] = accr[j] + brr;
        }
    }
}

// ---- fused GAT layer: score + online softmax + aggregate + mean + bias + relu ----
// one 64-lane wave per dst node; lane l covers cols 4l..4l+3 (head = l>>4)
__global__ __launch_bounds__(256) void gat_aggr_k(
    const float* __restrict__ xl, const float* __restrict__ xr,
    const float* __restrict__ eap, const float* __restrict__ We,
    const float* __restrict__ att,
    const int* __restrict__ row_start, const int* __restrict__ deg,
    const int* __restrict__ csr_src, const int* __restrict__ csr_eid,
    const float* __restrict__ bias, float* __restrict__ hout)
{
    int d = blockIdx.x * 4 + (threadIdx.x >> 6);
    int lane = threadIdx.x & 63;
    if (d >= N) return;
    int c4 = lane * 4;
    const float4 w0 = *(const float4*)&We[0 * HH + c4];
    const float4 w1 = *(const float4*)&We[1 * HH + c4];
    const float4 w2 = *(const float4*)&We[2 * HH + c4];
    const float4 w3 = *(const float4*)&We[3 * HH + c4];
    const float4 av = *(const float4*)&att[c4];
    const float4 vr = *(const float4*)&xr[(size_t)d * HH + c4];
    int start = row_start[d];
    int cnt = deg[d];
    int end = start + cnt;
    float m = -INFINITY, denom = 0.f;
    float ax = 0.f, ay = 0.f, az = 0.f, aw = 0.f;
    int idx = start;
    for (; idx + 2 <= end; idx += 2) {
        int s0 = csr_src[idx], s1 = csr_src[idx + 1];
        int e0 = csr_eid[idx], e1 = csr_eid[idx + 1];
        float4 a0 = *(const float4*)&eap[e0 * 4];
        float4 a1 = *(const float4*)&eap[e1 * 4];
        float4 vl0 = *(const float4*)&xl[(size_t)s0 * HH + c4];
        float4 vl1 = *(const float4*)&xl[(size_t)s1 * HH + c4];
        float q0 = vl0.x + vr.x + a0.x * w0.x + a0.y * w1.x + a0.z * w2.x + a0.w * w3.x;
        float q1 = vl0.y + vr.y + a0.x * w0.y + a0.y * w1.y + a0.z * w2.y + a0.w * w3.y;
        float q2 = vl0.z + vr.z + a0.x * w0.z + a0.y * w1.z + a0.z * w2.z + a0.w * w3.z;
        float q3 = vl0.w + vr.w + a0.x * w0.w + a0.y * w1.w + a0.z * w2.w + a0.w * w3.w;
        float r0 = vl1.x + vr.x + a1.x * w0.x + a1.y * w1.x + a1.z * w2.x + a1.w * w3.x;
        float r1 = vl1.y + vr.y + a1.x * w0.y + a1.y * w1.y + a1.z * w2.y + a1.w * w3.y;
        float r2 = vl1.z + vr.z + a1.x * w0.z + a1.y * w1.z + a1.z * w2.z + a1.w * w3.z;
        float r3 = vl1.w + vr.w + a1.x * w0.w + a1.y * w1.w + a1.z * w2.w + a1.w * w3.w;
        q0 = (q0 > 0.f) ? q0 : NEG * q0;
        q1 = (q1 > 0.f) ? q1 : NEG * q1;
        q2 = (q2 > 0.f) ? q2 : NEG * q2;
        q3 = (q3 > 0.f) ? q3 : NEG * q3;
        r0 = (r0 > 0.f) ? r0 : NEG * r0;
        r1 = (r1 > 0.f) ? r1 : NEG * r1;
        r2 = (r2 > 0.f) ? r2 : NEG * r2;
        r3 = (r3 > 0.f) ? r3 : NEG * r3;
        float p0 = q0 * av.x + q1 * av.y + q2 * av.z + q3 * av.w;
        float p1 = r0 * av.x + r1 * av.y + r2 * av.z + r3 * av.w;
        p0 += __shfl_xor(p0, 1, 64);
        p1 += __shfl_xor(p1, 1, 64);
        p0 += __shfl_xor(p0, 2, 64);
        p1 += __shfl_xor(p1, 2, 64);
        p0 += __shfl_xor(p0, 4, 64);
        p1 += __shfl_xor(p1, 4, 64);
        p0 += __shfl_xor(p0, 8, 64);
        p1 += __shfl_xor(p1, 8, 64);
        float newm = fmaxf(m, fmaxf(p0, p1));
        float so = expf(m - newm);
        float ex0 = expf(p0 - newm);
        float ex1 = expf(p1 - newm);
        denom = denom * so + ex0 + ex1;
        ax = ax * so + ex0 * vl0.x + ex1 * vl1.x;
        ay = ay * so + ex0 * vl0.y + ex1 * vl1.y;
        az = az * so + ex0 * vl0.z + ex1 * vl1.z;
        aw = aw * so + ex0 * vl0.w + ex1 * vl1.w;
        m = newm;
    }
    if (idx < end) {
        int s = csr_src[idx];
        int e = csr_eid[idx];
        float4 a = *(const float4*)&eap[e * 4];
        float4 vl = *(const float4*)&xl[(size_t)s * HH + c4];
        float q0 = vl.x + vr.x + a.x * w0.x + a.y * w1.x + a.z * w2.x + a.w * w3.x;
        float q1 = vl.y + vr.y + a.x * w0.y + a.y * w1.y + a.z * w2.y + a.w * w3.y;
        float q2 = vl.z + vr.z + a.x * w0.z + a.y * w1.z + a.z * w2.z + a.w * w3.z;
        float q3 = vl.w + vr.w + a.x * w0.w + a.y * w1.w + a.z * w2.w + a.w * w3.w;
        q0 = (q0 > 0.f) ? q0 : NEG * q0;
        q1 = (q1 > 0.f) ? q1 : NEG * q1;
        q2 = (q2 > 0.f) ? q2 : NEG * q2;
        q3 = (q3 > 0.f) ? q3 : NEG * q3;
        float p = q0 * av.x + q1 * av.y + q2 * av.z + q3 * av.w;
        p += __shfl_xor(p, 1, 64);
        p += __shfl_xor(p, 2, 64);
        p += __shfl_xor(p, 4, 64);
        p += __shfl_xor(p, 8, 64);
        float newm = fmaxf(m, p);
        float so = expf(m - newm);
        float ex = expf(p - newm);
        denom = denom * so + ex;
        ax = ax * so + ex * vl.x;
        ay = ay * so + ex * vl.y;
        az = az * so + ex * vl.z;
        aw = aw * so + ex * vl.w;
        m = newm;
    }
    float inv = 1.f / (denom + 1e-16f);
    ax *= inv; ay *= inv; az *= inv; aw *= inv;
    ax += __shfl_xor(ax, 16, 64); ax += __shfl_xor(ax, 32, 64);
    ay += __shfl_xor(ay, 16, 64); ay += __shfl_xor(ay, 32, 64);
    az += __shfl_xor(az, 16, 64); az += __shfl_xor(az, 32, 64);
    aw += __shfl_xor(aw, 16, 64); aw += __shfl_xor(aw, 32, 64);
    if (lane < 16) {
        float4 b = *(const float4*)&bias[c4];
        float4 o;
        o.x = fmaxf(0.25f * ax + b.x, 0.f);
        o.y = fmaxf(0.25f * ay + b.y, 0.f);
        o.z = fmaxf(0.25f * az + b.z, 0.f);
        o.w = fmaxf(0.25f * aw + b.w, 0.f);
        *(float4*)&hout[(size_t)d * HID + c4] = o;
    }
}

// ---- pooling: chunked segment sum (batch is sorted) ----
__global__ __launch_bounds__(256) void pool_k(
    const float* __restrict__ h, const int* __restrict__ batch,
    float* __restrict__ pooled)
{
    constexpr int CH = 16;
    int c = threadIdx.x & 63;
    int chunk = blockIdx.x * 4 + (threadIdx.x >> 6);
    int n0 = chunk * CH;
    if (n0 >= N) return;
    int nend = (n0 + CH < N) ? n0 + CH : N;
    float sum = 0.f;
    int curb = batch[n0];
    for (int n = n0; n < nend; ++n) {
        int b = batch[n];
        if (b != curb) {
            atomicAdd(&pooled[curb * HID + c], sum);
            sum = 0.f; curb = b;
        }
        sum += h[(size_t)n * HID + c];
    }
    atomicAdd(&pooled[curb * HID + c], sum);
}

// ---- MLP head: one block (64 threads) per graph ----
__global__ __launch_bounds__(64) void head_k(
    const float* __restrict__ pooled, const int* __restrict__ batch,
    const float* __restrict__ W_fc, const float* __restrict__ b_fc,
    const float* __restrict__ W_res, const float* __restrict__ b_res,
    const float* __restrict__ W_time, const float* __restrict__ b_time,
    float* __restrict__ out)
{
    int g = blockIdx.x;
    int c = threadIdx.x;
    int lo = 0, hi = N;
    while (lo < hi) { int mid = (lo + hi) >> 1; if (batch[mid] < g) lo = mid + 1; else hi = mid; }
    int start = lo;
    hi = N;
    while (lo < hi) { int mid = (lo + hi) >> 1; if (batch[mid] < g + 1) lo = mid + 1; else hi = mid; }
    int end = lo;
    float cnt = (float)(end - start);
    float p = pooled[g * HID + c] / fmaxf(cnt, 1.0f);
    __shared__ float ps[HID];
    ps[c] = p;
    __syncthreads();
    float gv = b_fc[c];
    for (int k = 0; k < HID; k++) gv += ps[k] * W_fc[k * HID + c];
    gv = fmaxf(gv, 0.f);
    float r = gv * W_res[c];
    float t = gv * W_time[c];
#pragma unroll
    for (int off = 32; off > 0; off >>= 1) {
        r += __shfl_down(r, off, 64);
        t += __shfl_down(t, off, 64);
    }
    if (c == 0) {
        out[g * 2 + 0] = r + b_res[0];
        out[g * 2 + 1] = t + b_time[0];
    }
}

} // namespace

extern "C" void kernel_launch(void* const* d_in, const int* in_sizes, int n_in,
                              void* d_out, int out_size, void* d_ws, size_t ws_size,
                              hipStream_t stream) {
    const float* x         = (const float*)d_in[0];
    const float* edge_attr = (const float*)d_in[1];
    const int*   edge_index= (const int*)d_in[2];
    const int*   batch     = (const int*)d_in[3];
    const float* W_et = (const float*)d_in[4];
    const float* b_et = (const float*)d_in[5];
    const float* W_uw = (const float*)d_in[6];
    const float* b_uw = (const float*)d_in[7];
    const float* W_ua = (const float*)d_in[8];
    const float* b_ua = (const float*)d_in[9];
    const float* Wl0  = (const float*)d_in[10];
    const float* bl0  = (const float*)d_in[11];
    const float* Wr0  = (const float*)d_in[12];
    const float* br0  = (const float*)d_in[13];
    const float* att0 = (const float*)d_in[14];
    const float* We0  = (const float*)d_in[15];
    const float* bias0= (const float*)d_in[16];
    const float* Wl1  = (const float*)d_in[17];
    const float* bl1  = (const float*)d_in[18];
    const float* Wr1  = (const float*)d_in[19];
    const float* br1  = (const float*)d_in[20];
    const float* att1 = (const float*)d_in[21];
    const float* We1  = (const float*)d_in[22];
    const float* bias1= (const float*)d_in[23];
    const float* W_fc = (const float*)d_in[24];
    const float* b_fc = (const float*)d_in[25];
    const float* W_res= (const float*)d_in[26];
    const float* b_res= (const float*)d_in[27];
    const float* W_time=(const float*)d_in[28];
    const float* b_time=(const float*)d_in[29];

    const int* src = edge_index;     // row 0
    const int* dst = edge_index + E; // row 1

    // workspace layout
    float* ws    = (float*)d_ws;
    float* eap   = ws;                        // E*4
    float* xl    = eap + (size_t)E * 4;       // N*HH
    float* xr    = xl  + (size_t)N * HH;      // N*HH
    float* h1    = xr  + (size_t)N * HH;      // N*HID
    float* h2    = h1  + (size_t)N * HID;     // N*HID
    float* pooled= h2  + (size_t)N * HID;     // G*HID
    float* WlT0  = pooled + (size_t)G * HID;  // 128*256
    float* WrT0  = WlT0 + 128 * HH;           // 128*256
    float* WlT1  = WrT0 + 128 * HH;           // 64*256
    float* WrT1  = WlT1 + 64 * HH;            // 64*256
    int*   deg      = (int*)(WrT1 + 64 * HH); // N
    int*   row_start= deg + N;                // N
    int*   cursor   = row_start + N;          // N
    int*   bsum     = cursor + N;             // 256
    int*   csr_src  = bsum + 256;             // E
    int*   csr_eid  = csr_src + E;            // E

    dim3 b256(256);
    const int NB = (N + 255) / 256; // 196

    // edge features + deg=0
    edge_feat_k<<<(E + 255) / 256, b256, 0, stream>>>(
        edge_attr, W_et, b_et, W_uw, b_uw, W_ua, b_ua, eap, deg);
    // weight packs
    pack_w_k<<<(128 * HH + 255) / 256, b256, 0, stream>>>(Wl0, WlT0, 128);
    pack_w_k<<<(128 * HH + 255) / 256, b256, 0, stream>>>(Wr0, WrT0, 128);
    pack_w_k<<<(64 * HH + 255) / 256, b256, 0, stream>>>(Wl1, WlT1, 64);
    pack_w_k<<<(64 * HH + 255) / 256, b256, 0, stream>>>(Wr1, WrT1, 64);
    // CSR build
    hist_k<<<(E + 255) / 256, b256, 0, stream>>>(dst, deg);
    scan1_k<<<NB, b256, 0, stream>>>(deg, row_start, bsum);
    scan2_k<<<1, b256, 0, stream>>>(bsum, NB, pooled);
    scan3_k<<<NB, b256, 0, stream>>>(row_start, bsum, cursor);
    scatter_k<<<(E + 255) / 256, b256, 0, stream>>>(src, dst, cursor, csr_src, csr_eid);

    // ---------- layer 0 ----------
    node_proj_k<128><<<(N + 15) / 16, b256, 0, stream>>>(x, WlT0, bl0, WrT0, br0, xl, xr);
    gat_aggr_k<<<(N + 3) / 4, b256, 0, stream>>>(
        xl, xr, eap, We0, att0, row_start, deg, csr_src, csr_eid, bias0, h1);

    // ---------- layer 1 ----------
    node_proj_k<64><<<(N + 15) / 16, b256, 0, stream>>>(h1, WlT1, bl1, WrT1, br1, xl, xr);
    gat_aggr_k<<<(N + 3) / 4, b256, 0, stream>>>(
        xl, xr, eap, We1, att1, row_start, deg, csr_src, csr_eid, bias1, h2);

    // ---------- pooling + head ----------
    pool_k<<<((N + 15) / 16 + 3) / 4, b256, 0, stream>>>(h2, batch, pooled);
    head_k<<<G, dim3(64), 0, stream>>>(
        pooled, batch, W_fc, b_fc, W_res, b_res, W_time, b_time, (float*)d_out);
}